// Round 4
// baseline (148.252 us; speedup 1.0000x reference)
//
#include <hip/hip_runtime.h>
#include <hip/hip_bf16.h>

// ---------------------------------------------------------------------------
// EmbeddingGATHead: pool -> GATv2 (2 layers, 4 heads, block-diag mask) ->
// residual -> part-mean -> BN.
// Round 4: LDS-free, barrier-free GEMM. Each wave = 192 rows x 16 cols,
// A/B fragments loaded straight from global in MFMA layout; P partials bf16.
// Node order: n = p*32 + b.  Instance g = n // 6, valid iff (n % 6) < nps[g].
// ---------------------------------------------------------------------------

#define NNODES 192
#define CFEAT  2048

typedef __attribute__((ext_vector_type(8))) short bf16x8;   // 8 bf16 = 4 VGPR
typedef __attribute__((ext_vector_type(4))) float f32x4;

__device__ inline unsigned f2bf(float f) {                 // RNE f32 -> bf16
    union { float f; unsigned u; } v; v.f = f;
    unsigned u = v.u;
    u += 0x7FFFu + ((u >> 16) & 1u);
    return u >> 16;
}
__device__ inline float bf2f(unsigned short u) {
    union { unsigned u; float f; } v; v.u = (unsigned)u << 16;
    return v.f;
}

// ---- 1. Global average pool: features [32][12288][16][8] -> pool [192][2048]
__global__ __launch_bounds__(256) void pool_kernel(const float* __restrict__ F,
                                                   float* __restrict__ POOL,
                                                   unsigned short* __restrict__ POOLB) {
    int wave = threadIdx.x >> 6, lane = threadIdx.x & 63;
    #pragma unroll
    for (int it = 0; it < 12; ++it) {
        int dr = blockIdx.x * 4 + wave + it * 16384;   // [0, 196608)
        int r0 = dr * 2;                               // (n,c) pair index
        int n = r0 >> 11, c0 = r0 & 2047;
        int p = n >> 5, b = n & 31;                    // n = p*32 + b
        const float* src = F + (((size_t)b * 12288 + (size_t)p * 2048 + c0) << 7);
        float4 v = *(const float4*)(src + (lane << 2));
        float acc = (v.x + v.y) + (v.z + v.w);
        acc += __shfl_down(acc, 16);
        acc += __shfl_down(acc, 8);
        acc += __shfl_down(acc, 4);
        acc += __shfl_down(acc, 2);
        acc += __shfl_down(acc, 1);
        if ((lane & 31) == 0) {                        // lanes 0 and 32
            int r = r0 + (lane >> 5);
            float m = acc * (1.0f / 128.0f);
            POOL[r] = m;
            POOLB[r] = (unsigned short)f2bf(m);
        }
    }
}

// ---- 2. LDS-free bf16 MFMA GEMM, split-K=8.
// grid (64, 8): block bx covers cols [bx*64, bx*64+64); wave w owns 16 of them
// (192 rows x 16 cols = 12 MFMA frags). K chunk per block: [sk*256, sk*256+256).
// A-frag: lane holds X[fi*16 + (l&15)][k0 + (l>>4)*8 + 0..7]  (one 16B load)
// B-frag: lane holds W[k0 + (l>>4)*8 + 0..7][col] (8 strided dwords, f2bf inline)
__global__ __launch_bounds__(256) void gemm_kernel(
    const unsigned short* __restrict__ X,    // bf16 [192][2048]
    const float* __restrict__ WL,            // fp32 [4][2048][512] (layer slice)
    const float* __restrict__ WR,
    unsigned short* __restrict__ P) {        // bf16 [8][192][4096]
    int bx = blockIdx.x, sk = blockIdx.y;
    int t = threadIdx.x, w = t >> 6, l = t & 63;
    int lr = l & 15, lg = l >> 4;
    int kbeg = sk << 8;

    const float* Wb = (bx >= 32 ? WR : WL)
                    + (size_t)((bx & 31) >> 3) * (2048 * 512)   // head
                    + ((bx & 7) << 6) + (w << 4) + lr;          // col within head
    const unsigned short* Xp = X + (size_t)lr * 2048 + kbeg + lg * 8;

    f32x4 acc[12];
    #pragma unroll
    for (int i = 0; i < 12; ++i) acc[i] = {0.f, 0.f, 0.f, 0.f};

    for (int step = 0; step < 8; ++step) {
        int k0 = step << 5;
        const float* wp = Wb + (size_t)(kbeg + k0 + lg * 8) * 512;
        float b0 = wp[0],        b1 = wp[512],      b2 = wp[2 * 512], b3 = wp[3 * 512];
        float b4 = wp[4 * 512],  b5 = wp[5 * 512],  b6 = wp[6 * 512], b7 = wp[7 * 512];
        uint4 bb;
        bb.x = f2bf(b0) | (f2bf(b1) << 16);
        bb.y = f2bf(b2) | (f2bf(b3) << 16);
        bb.z = f2bf(b4) | (f2bf(b5) << 16);
        bb.w = f2bf(b6) | (f2bf(b7) << 16);
        bf16x8 bfr = __builtin_bit_cast(bf16x8, bb);
        #pragma unroll
        for (int fi = 0; fi < 12; ++fi) {
            bf16x8 af = *(const bf16x8*)(Xp + (size_t)fi * 16 * 2048 + k0);
            acc[fi] = __builtin_amdgcn_mfma_f32_16x16x32_bf16(af, bfr, acc[fi], 0, 0, 0);
        }
    }

    // D layout: row = (l>>4)*4 + reg, col = l&15  [m89-verified]
    unsigned short* Pp = P + (size_t)sk * (192 * 4096)
                       + (size_t)(lg * 4) * 4096 + (bx << 6) + (w << 4) + lr;
    #pragma unroll
    for (int fi = 0; fi < 12; ++fi)
        #pragma unroll
        for (int j = 0; j < 4; ++j)
            Pp[(size_t)(fi * 16 + j) * 4096] = (unsigned short)f2bf(acc[fi][j]);
}

// ---- 3. Attention per (instance g, head h), fused split-K reduce + bias.
template <int LAYER>
__global__ __launch_bounds__(256) void attn_kernel(
    const unsigned short* __restrict__ P,      // bf16 [8][192][4096]
    const float* __restrict__ BL,              // [4][512] bias lin_l (layer slice)
    const float* __restrict__ BR,              // [4][512] bias lin_r
    const float* __restrict__ ATT,             // [4][512] (layer slice)
    const float* __restrict__ GBIAS,           // [2048]   (layer slice)
    const int* __restrict__ NPS,               // [32]
    const float* __restrict__ POOL,            // [192][2048] (layer 1 only)
    float* __restrict__ OUTF,                  // layer 1: graph_feat fp32
    unsigned short* __restrict__ OUTB) {       // layer 0: x1 bf16
    __shared__ float xls[6][512];
    __shared__ float xrs[6][512];
    __shared__ float atts[512];
    __shared__ float s_sm[6][6];
    __shared__ float alpha[6][6];

    int g = blockIdx.x, h = blockIdx.y;
    int tid = threadIdx.x;
    int cnt = NPS[g];

    for (int idx = tid; idx < 6 * 512; idx += 256) {
        int q = idx >> 9, d = idx & 511;
        int col = h * 512 + d;
        size_t base = (size_t)(g * 6 + q) * 4096 + col;
        float sl = BL[col], sr = BR[col];
        #pragma unroll
        for (int sk = 0; sk < 8; ++sk) {
            const unsigned short* Ps = P + (size_t)sk * (192 * 4096) + base;
            sl += bf2f(Ps[0]);
            sr += bf2f(Ps[2048]);
        }
        xls[q][d] = sl;
        xrs[q][d] = sr;
    }
    for (int d = tid; d < 512; d += 256) atts[d] = ATT[h * 512 + d];
    __syncthreads();

    // s[i][j] = sum_d att[d] * leaky_relu(xr[i][d] + xl[j][d], 0.2)
    int wv = tid >> 6, lane = tid & 63;
    for (int p = wv; p < 36; p += 4) {
        int i = p / 6, j = p % 6;
        float acc = 0.f;
        #pragma unroll
        for (int u = 0; u < 8; ++u) {
            int d = lane + u * 64;
            float v = xrs[i][d] + xls[j][d];
            v = (v >= 0.f) ? v : 0.2f * v;
            acc = fmaf(atts[d], v, acc);
        }
        #pragma unroll
        for (int off = 32; off; off >>= 1) acc += __shfl_down(acc, off);
        if (lane == 0) s_sm[i][j] = acc;
    }
    __syncthreads();

    // softmax per row over neighbor set (valid i -> all valid j; invalid -> self)
    if (tid < 6) {
        int i = tid;
        bool iv = i < cnt;
        float mx;
        if (iv) {
            mx = -1e30f;
            for (int j = 0; j < cnt; ++j) mx = fmaxf(mx, s_sm[i][j]);
        } else {
            mx = s_sm[i][i];
        }
        float e[6], sum = 0.f;
        for (int j = 0; j < 6; ++j) {
            bool nb = iv ? (j < cnt) : (j == i);
            e[j] = nb ? expf(s_sm[i][j] - mx) : 0.f;
            sum += e[j];
        }
        float inv = 1.f / sum;
        for (int j = 0; j < 6; ++j) alpha[i][j] = e[j] * inv;
    }
    __syncthreads();

    for (int idx = tid; idx < 6 * 512; idx += 256) {
        int q = idx >> 9, d = idx & 511;
        float acc = 0.f;
        #pragma unroll
        for (int j = 0; j < 6; ++j) acc = fmaf(alpha[q][j], xls[j][d], acc);
        int col = h * 512 + d;
        size_t off = (size_t)(g * 6 + q) * 2048 + col;
        float v = acc + GBIAS[col];
        if (LAYER == 0) {
            v = (v > 0.f) ? v : expm1f(v);      // ELU
            OUTB[off] = (unsigned short)f2bf(v);
        } else {
            OUTF[off] = v + POOL[off];          // graph_feat = x + pool
        }
    }
}

// ---- 4. Part-mean + BN
__global__ __launch_bounds__(256) void final_kernel(
    const float* __restrict__ GF, const float* __restrict__ GAMMA,
    const float* __restrict__ MEAN, const float* __restrict__ VAR,
    float* __restrict__ OUTP) {
    int idx = blockIdx.x * 256 + threadIdx.x;   // [0, 65536)
    int c = idx & 2047, b = idx >> 11;
    float acc = 0.f;
    #pragma unroll
    for (int p = 0; p < 6; ++p) acc += GF[(size_t)(p * 32 + b) * 2048 + c];
    acc *= (1.f / 6.f);
    OUTP[idx] = GAMMA[c] * (acc - MEAN[c]) * rsqrtf(VAR[c] + 1e-5f);
}

extern "C" void kernel_launch(void* const* d_in, const int* in_sizes, int n_in,
                              void* d_out, int out_size, void* d_ws, size_t ws_size,
                              hipStream_t stream) {
    const float* F     = (const float*)d_in[0];
    const int*   nps   = (const int*)d_in[1];
    const float* Wl    = (const float*)d_in[2];
    const float* bl    = (const float*)d_in[3];
    const float* Wr    = (const float*)d_in[4];
    const float* br    = (const float*)d_in[5];
    const float* att   = (const float*)d_in[6];
    const float* gb    = (const float*)d_in[7];
    const float* gamma = (const float*)d_in[8];
    const float* mean  = (const float*)d_in[9];
    const float* var   = (const float*)d_in[10];
    float* out = (float*)d_out;
    float* wsf = (float*)d_ws;

    const size_t SZ = (size_t)NNODES * CFEAT;   // 393216
    float* pool = wsf;                                        // [192][2048] f32
    float* gf   = wsf + SZ;                                   // [192][2048] f32
    unsigned short* P     = (unsigned short*)(wsf + 2 * SZ);  // bf16 [8][192][4096] = 8*SZ floats
    unsigned short* poolb = (unsigned short*)(wsf + 10 * SZ); // bf16 [192][2048]
    unsigned short* x1b   = (unsigned short*)(wsf + 11 * SZ); // bf16 [192][2048]

    const size_t WOFF = 4ull * 2048 * 512;       // per-layer weight stride

    // 1. pool (fp32 + bf16)
    pool_kernel<<<dim3(4096), dim3(256), 0, stream>>>(F, pool, poolb);

    // 2. layer 0
    gemm_kernel<<<dim3(64, 8), dim3(256), 0, stream>>>(poolb, Wl, Wr, P);
    attn_kernel<0><<<dim3(32, 4), dim3(256), 0, stream>>>(P, bl, br, att, gb, nps,
                                                          nullptr, nullptr, x1b);

    // 3. layer 1
    gemm_kernel<<<dim3(64, 8), dim3(256), 0, stream>>>(x1b, Wl + WOFF, Wr + WOFF, P);
    attn_kernel<1><<<dim3(32, 4), dim3(256), 0, stream>>>(P, bl + 2048, br + 2048,
                                                          att + 2048, gb + 2048,
                                                          nps, pool, gf, nullptr);

    // 4. part-mean + BN
    final_kernel<<<dim3(256), dim3(256), 0, stream>>>(gf, gamma, mean, var, out);
}